// Round 11
// baseline (118.591 us; speedup 1.0000x reference)
//
#include <hip/hip_runtime.h>

// ContrastiveLoss on MI355X.
// Measured facts driving this version:
//   - label scan aggregate ceiling scales weakly with scan-CU count:
//     128 CUs -> 4.1 TB/s (r4), 256 CUs -> 4.9 TB/s (r8). Per-XCD L2-fill
//     path saturation; more scan CUs still helps.
//   - nf (2MB) is L2-resident per XCD -> GEMM B-reads don't contend at LLC.
//   - r10 bug: 1024 blocks at 3-blocks/CU residency -> 256-block serial tail
//     (+17us). Fix: grid EXACTLY 768 = 3 x 256 CUs, launch_bounds(256,3).
// Pipeline:
//   k1 normalize: feats fp32 [8192][128] -> nf bf16 (ws)
//   k2 split-pool (768 blocks, all co-resident):
//      (b&255)<192 -> scan pool (192 CUs, 576 blocks): interleaved whole
//        2048-vec4 batches bi = s, s+576, ... < 8192 (no waste, all in-bounds,
//        8 u32x4 loads in flight per lane).
//      else -> GEMM pool (64 CUs, 192 blocks): stride-loop u = p, p+192, ...
//        over 512 units (64 rows x 2048 cols, r4's LDS 64x64-tile body,
//        fixed-max sum-of-exp, diag skipped, wn-distinct lpart slots).
//   k3 finalize: lse = M + log(sum of 8 partials); pos = nf_i.nf_p/T;
//      block reduce -> atomicAdd(mean term) into d_out (memset to 0 first).
// ws: 2MB nf + 256KB lpart(8 slots) + 32KB pos_idx.

#define NN 8192
#define DD 128

typedef __bf16 bf16x8 __attribute__((ext_vector_type(8)));
typedef float f32x4 __attribute__((ext_vector_type(4)));
typedef unsigned int u32x4 __attribute__((ext_vector_type(4)));

constexpr float kM     = 1.0f / 0.07f;                    // fixed max bound (cos<=1)
constexpr float kScale = 1.4426950408889634f / 0.07f;     // log2(e)/T
constexpr float kLn2   = 0.6931471805599453f;

__device__ inline unsigned short f2bf(float f) {
  unsigned int u = __float_as_uint(f);
  unsigned int r = (u + 0x7FFFu + ((u >> 16) & 1u)) >> 16;  // RNE, no NaN inputs
  return (unsigned short)r;
}

// ---------------- k1: normalize rows, store bf16 ----------------
__global__ __launch_bounds__(256) void k_normalize(const float* __restrict__ feats,
                                                   unsigned short* __restrict__ nfb) {
  int tid = threadIdx.x;
  int lane = tid & 63;
  int row = blockIdx.x * 4 + (tid >> 6);
  float2 f = *(const float2*)(feats + (size_t)row * DD + lane * 2);
  float ss = f.x * f.x + f.y * f.y;
  #pragma unroll
  for (int m = 1; m < 64; m <<= 1) ss += __shfl_xor(ss, m);
  float rn = 1.0f / fmaxf(sqrtf(ss), 1e-8f);
  unsigned int lo = f2bf(f.x * rn), hi = f2bf(f.y * rn);
  *(unsigned int*)(nfb + (size_t)row * DD + lane * 2) = lo | (hi << 16);
}

// ---------------- k2: split-pool scan / GEMM+LSE ----------------
__global__ __launch_bounds__(256, 3) void k_fused(const unsigned short* __restrict__ nfb,
                                                  const int* __restrict__ label,
                                                  float* __restrict__ lpart,
                                                  int* __restrict__ pos_idx) {
  __shared__ __align__(16) unsigned short ldsB[64 * DD];  // 16KB, XOR-swizzled rows
  int b = blockIdx.x;              // 0..767 (= 3 x 256, all co-resident)
  int tid = threadIdx.x;
  int c = b & 255;                 // CU selector -> pool purity
  if (c < 192) {
    // ---- scan pool: 576 blocks; interleaved whole batches, no waste ----
    int s = (b >> 8) * 192 + c;                // 0..575
    const u32x4* L = (const u32x4*)label;
    for (int bi = s; bi < 8192; bi += 576) {   // 14-15 batches of 2048 vec4
      int base = bi * 2048 + tid;
      u32x4 v[8];
      #pragma unroll
      for (int j = 0; j < 8; j++)
        v[j] = L[base + j * 256];
      unsigned any = 0;
      #pragma unroll
      for (int j = 0; j < 8; j++) any |= v[j][0] | v[j][1] | v[j][2] | v[j][3];
      if (any) {
        #pragma unroll
        for (int j = 0; j < 8; j++) {
          if (v[j][0] | v[j][1] | v[j][2] | v[j][3]) {
            int gi = (base + j * 256) * 4;
            int row = gi >> 13, col = gi & (NN - 1);
            if (v[j][0] == 1u) pos_idx[row] = col;
            if (v[j][1] == 1u) pos_idx[row] = col + 1;
            if (v[j][2] == 1u) pos_idx[row] = col + 2;
            if (v[j][3] == 1u) pos_idx[row] = col + 3;
          }
        }
      }
    }
  } else {
    // ---- GEMM pool: 192 blocks stride-loop 512 units (64 rows x 2048 cols) ----
    int p = (b >> 8) * 64 + (c - 192);         // 0..191
    int lane = tid & 63, w = tid >> 6;
    int wm = w >> 1, wn = w & 1;               // 2x2 wave grid
    int lg = lane >> 4;                        // lane group 0..3
    int ll = lane & 15;
    int slr = tid >> 4;                        // staging: local row base
    int sch = tid & 15;                        // staging: 16B chunk

    for (int u = p; u < 512; u += 192) {
      int r0 = (u >> 2) * 64;
      int c0 = (u & 3) * 2048;

      // A fragments: row = ll within 16-row subtile, k = kc*32 + lg*8 .. +7
      bf16x8 afr[2][4];
      #pragma unroll
      for (int ms = 0; ms < 2; ms++) {
        const unsigned short* arow = nfb + (size_t)(r0 + wm * 32 + ms * 16 + ll) * DD + lg * 8;
        #pragma unroll
        for (int kc = 0; kc < 4; kc++)
          afr[ms][kc] = *(const bf16x8*)(arow + kc * 32);
      }

      float lacc[2][4] = {{0.f, 0.f, 0.f, 0.f}, {0.f, 0.f, 0.f, 0.f}};

      for (int ct = 0; ct < 32; ct++) {
        int ctile = c0 + ct * 64;
        __syncthreads();
        // stage 64x128 bf16 B tile (rows = global cols), swizzled
        #pragma unroll
        for (int pp = 0; pp < 4; pp++) {
          int row = pp * 16 + slr;
          u32x4 v = *(const u32x4*)(nfb + (size_t)(ctile + row) * DD + sch * 8);
          *(u32x4*)((char*)ldsB + row * 256 + ((sch * 16) ^ ((row & 7) << 4))) = v;
        }
        __syncthreads();

        f32x4 acc[2][2] = {{{0.f,0.f,0.f,0.f},{0.f,0.f,0.f,0.f}},
                           {{0.f,0.f,0.f,0.f},{0.f,0.f,0.f,0.f}}};
        #pragma unroll
        for (int ns = 0; ns < 2; ns++) {
          int brow = wn * 32 + ns * 16 + ll;
          const char* bbase = (const char*)ldsB + brow * 256;
          int sw = (brow & 7) << 4;
          #pragma unroll
          for (int kc = 0; kc < 4; kc++) {
            bf16x8 bfr = *(const bf16x8*)(bbase + ((kc * 64 + lg * 16) ^ sw));
            acc[0][ns] = __builtin_amdgcn_mfma_f32_16x16x32_bf16(afr[0][kc], bfr, acc[0][ns], 0, 0, 0);
            acc[1][ns] = __builtin_amdgcn_mfma_f32_16x16x32_bf16(afr[1][kc], bfr, acc[1][ns], 0, 0, 0);
          }
        }

        // fixed-max sum of exp; C layout: col=ll, row=lg*4+r
        bool mayDiag = (ctile < r0 + 64) && (r0 < ctile + 64);
        if (mayDiag) {
          #pragma unroll
          for (int ms = 0; ms < 2; ms++) {
            int growb = r0 + wm * 32 + ms * 16 + lg * 4;
            #pragma unroll
            for (int ns = 0; ns < 2; ns++) {
              int gcol = ctile + wn * 32 + ns * 16 + ll;
              #pragma unroll
              for (int r = 0; r < 4; r++) {
                float sv = (growb + r == gcol) ? -3.0e38f : acc[ms][ns][r];
                lacc[ms][r] += __builtin_amdgcn_exp2f((sv - 1.0f) * kScale);
              }
            }
          }
        } else {
          #pragma unroll
          for (int ms = 0; ms < 2; ms++)
            #pragma unroll
            for (int ns = 0; ns < 2; ns++)
              #pragma unroll
              for (int r = 0; r < 4; r++)
                lacc[ms][r] += __builtin_amdgcn_exp2f((acc[ms][ns][r] - 1.0f) * kScale);
        }
      }

      // reduce partial l across the 16 lanes of each group; wn-distinct slots.
      #pragma unroll
      for (int ms = 0; ms < 2; ms++)
        #pragma unroll
        for (int r = 0; r < 4; r++) {
          float v = lacc[ms][r];
          v += __shfl_xor(v, 1); v += __shfl_xor(v, 2);
          v += __shfl_xor(v, 4); v += __shfl_xor(v, 8);
          lacc[ms][r] = v;
        }
      if (ll == 0) {
        int slot = (u & 3) * 2 + wn;
        #pragma unroll
        for (int ms = 0; ms < 2; ms++)
          #pragma unroll
          for (int r = 0; r < 4; r++) {
            int grow = r0 + wm * 32 + ms * 16 + lg * 4 + r;
            lpart[(size_t)slot * NN + grow] = lacc[ms][r];
          }
      }
    }
  }
}

// ---------------- k3: per-row lse + positive, atomic mean ----------------
__global__ __launch_bounds__(256) void k_finalize(const unsigned short* __restrict__ nfb,
                                                  const float* __restrict__ lpart,
                                                  const int* __restrict__ pos_idx,
                                                  float* __restrict__ out) {
  int i = blockIdx.x * 256 + threadIdx.x;
  float l = 0.f;
  #pragma unroll
  for (int s = 0; s < 8; s++) l += lpart[(size_t)s * NN + i];
  float lse = kM + __builtin_amdgcn_logf(l) * kLn2;
  int p = pos_idx[i] & (NN - 1);
  const u32x4* ri = (const u32x4*)(nfb + (size_t)i * DD);
  const u32x4* rp = (const u32x4*)(nfb + (size_t)p * DD);
  float dot = 0.f;
  #pragma unroll
  for (int c = 0; c < 16; c++) {
    u32x4 a = ri[c], bb = rp[c];
    #pragma unroll
    for (int e = 0; e < 4; e++) {
      float al = __uint_as_float(a[e] << 16), ah = __uint_as_float(a[e] & 0xFFFF0000u);
      float bl = __uint_as_float(bb[e] << 16), bh = __uint_as_float(bb[e] & 0xFFFF0000u);
      dot += al * bl + ah * bh;
    }
  }
  float val = lse - dot * kM;   // pos = dot / T
  #pragma unroll
  for (int m = 1; m < 64; m <<= 1) val += __shfl_xor(val, m);
  __shared__ float wsum[4];
  if ((threadIdx.x & 63) == 0) wsum[threadIdx.x >> 6] = val;
  __syncthreads();
  if (threadIdx.x == 0)
    atomicAdd(out, (wsum[0] + wsum[1] + wsum[2] + wsum[3]) * (1.0f / (float)NN));
}

extern "C" void kernel_launch(void* const* d_in, const int* in_sizes, int n_in,
                              void* d_out, int out_size, void* d_ws, size_t ws_size,
                              hipStream_t stream) {
  (void)in_sizes; (void)n_in; (void)out_size; (void)ws_size;
  const float* feats = (const float*)d_in[0];
  const int* label = (const int*)d_in[1];
  float* out = (float*)d_out;

  char* ws = (char*)d_ws;
  unsigned short* nfb = (unsigned short*)ws;                    // 2 MB
  float* lpart = (float*)(ws + 2 * 1024 * 1024);                // 256 KB (8 slots)
  int* pos_idx = (int*)(ws + 2 * 1024 * 1024 + 262144);         // 32 KB

  hipMemsetAsync(out, 0, sizeof(float), stream);
  k_normalize<<<NN / 4, 256, 0, stream>>>(feats, nfb);
  k_fused<<<768, 256, 0, stream>>>(nfb, label, lpart, pos_idx);
  k_finalize<<<NN / 256, 256, 0, stream>>>(nfb, lpart, pos_idx, out);
}

// Round 12
// 115.121 us; speedup vs baseline: 1.0301x; 1.0301x over previous
//
#include <hip/hip_runtime.h>

// ContrastiveLoss on MI355X.
// Model fitted to r3-r11: total ~= max(scan(f), gemm(f)) + 8us; r4 (128/128
// CU split) was the pool optimum at 71.3us. Shared wall hypothesis: XCD TCC
// port path (L2 hit+miss combined) ~8-9 TB/s chip-wide; k2 moves scan 268MB
// + GEMM-B 268MB ~= 540MB -> ~63us regardless of CU arrangement.
// This round: halve GEMM TCC bytes via 128-row x 1024-col units (the staged
// 64x128 B-tile serves 2x the output rows). Everything else = r4 exactly.
// Pipeline:
//   k1 normalize: feats fp32 [8192][128] -> nf bf16 (ws)
//   k2 fused (1024 blocks, bit-3 type split as r4):
//      (b&8)==0 -> scan half: 512 blocks, 8-deep u32x4 batches over label.
//      (b&8)!=0 -> GEMM half: 512 units of 128 rows x 1024 cols; LDS-staged
//        64x128 swizzled B-tile per 64-col step; 2x2 wave grid (wm = 64-row
//        half, wn = 32-col half); fixed-max sum-of-exp; diag skipped;
//        slot = (g&7)*2+wn (16 lpart slots).
//   k3 finalize: lse = M + log(sum of 16 partials); pos = nf_i.nf_p/T;
//      block reduce -> atomicAdd(mean) into d_out (memset to 0 first).
// ws: 2MB nf + 512KB lpart(16 slots) + 32KB pos_idx.

#define NN 8192
#define DD 128

typedef __bf16 bf16x8 __attribute__((ext_vector_type(8)));
typedef float f32x4 __attribute__((ext_vector_type(4)));
typedef unsigned int u32x4 __attribute__((ext_vector_type(4)));

constexpr float kM     = 1.0f / 0.07f;                    // fixed max bound (cos<=1)
constexpr float kScale = 1.4426950408889634f / 0.07f;     // log2(e)/T
constexpr float kLn2   = 0.6931471805599453f;

__device__ inline unsigned short f2bf(float f) {
  unsigned int u = __float_as_uint(f);
  unsigned int r = (u + 0x7FFFu + ((u >> 16) & 1u)) >> 16;  // RNE, no NaN inputs
  return (unsigned short)r;
}

// ---------------- k1: normalize rows, store bf16 ----------------
__global__ __launch_bounds__(256) void k_normalize(const float* __restrict__ feats,
                                                   unsigned short* __restrict__ nfb) {
  int tid = threadIdx.x;
  int lane = tid & 63;
  int row = blockIdx.x * 4 + (tid >> 6);
  float2 f = *(const float2*)(feats + (size_t)row * DD + lane * 2);
  float ss = f.x * f.x + f.y * f.y;
  #pragma unroll
  for (int m = 1; m < 64; m <<= 1) ss += __shfl_xor(ss, m);
  float rn = 1.0f / fmaxf(sqrtf(ss), 1e-8f);
  unsigned int lo = f2bf(f.x * rn), hi = f2bf(f.y * rn);
  *(unsigned int*)(nfb + (size_t)row * DD + lane * 2) = lo | (hi << 16);
}

// ---------------- k2: fused GEMM+LSE / label scan (r4 structure) ----------------
__global__ void k_fused(const unsigned short* __restrict__ nfb,
                        const int* __restrict__ label,
                        float* __restrict__ lpart,
                        int* __restrict__ pos_idx) {
  __shared__ __align__(16) unsigned short ldsB[64 * DD];  // 16KB, XOR-swizzled rows
  int b = blockIdx.x;
  int tid = threadIdx.x;
  int sub = ((b >> 4) << 3) | (b & 7);       // 0..511 per type (bit-3 split)
  if (b & 8) {
    // ---- GEMM half: unit = 128 rows x 1024 cols ----
    int g = sub;                     // 0..511
    int r0 = (g >> 3) * 128;         // 64 row-bands
    int c0 = (g & 7) * 1024;         // 8 col-strips
    int lane = tid & 63, w = tid >> 6;
    int wm = w >> 1, wn = w & 1;     // wm: 64-row half; wn: 32-col half
    int lg = lane >> 4;              // lane group 0..3
    int ll = lane & 15;

    // A fragments: 64 rows per wave = 4 ms subtiles; k = kc*32 + lg*8
    bf16x8 afr[4][4];
    #pragma unroll
    for (int ms = 0; ms < 4; ms++) {
      const unsigned short* arow = nfb + (size_t)(r0 + wm * 64 + ms * 16 + ll) * DD + lg * 8;
      #pragma unroll
      for (int kc = 0; kc < 4; kc++)
        afr[ms][kc] = *(const bf16x8*)(arow + kc * 32);
    }

    float lacc[4][4];
    #pragma unroll
    for (int ms = 0; ms < 4; ms++)
      #pragma unroll
      for (int r = 0; r < 4; r++) lacc[ms][r] = 0.f;

    int slr = tid >> 4;   // staging: local row base
    int sch = tid & 15;   // staging: 16B chunk

    for (int ct = 0; ct < 16; ct++) {
      int ctile = c0 + ct * 64;
      __syncthreads();
      // stage 64x128 bf16 B tile (rows = global cols), swizzled
      #pragma unroll
      for (int p = 0; p < 4; p++) {
        int row = p * 16 + slr;
        u32x4 v = *(const u32x4*)(nfb + (size_t)(ctile + row) * DD + sch * 8);
        *(u32x4*)((char*)ldsB + row * 256 + ((sch * 16) ^ ((row & 7) << 4))) = v;
      }
      __syncthreads();

      f32x4 acc[4][2];
      #pragma unroll
      for (int ms = 0; ms < 4; ms++)
        #pragma unroll
        for (int ns = 0; ns < 2; ns++) acc[ms][ns] = (f32x4){0.f, 0.f, 0.f, 0.f};
      #pragma unroll
      for (int ns = 0; ns < 2; ns++) {
        int brow = wn * 32 + ns * 16 + ll;
        const char* bbase = (const char*)ldsB + brow * 256;
        int sw = (brow & 7) << 4;
        #pragma unroll
        for (int kc = 0; kc < 4; kc++) {
          bf16x8 bfr = *(const bf16x8*)(bbase + ((kc * 64 + lg * 16) ^ sw));
          #pragma unroll
          for (int ms = 0; ms < 4; ms++)
            acc[ms][ns] = __builtin_amdgcn_mfma_f32_16x16x32_bf16(afr[ms][kc], bfr, acc[ms][ns], 0, 0, 0);
        }
      }

      // fixed-max sum of exp; C layout: col=ll, row=lg*4+r
      bool mayDiag = (ctile < r0 + 128) && (r0 < ctile + 64);
      if (mayDiag) {
        #pragma unroll
        for (int ms = 0; ms < 4; ms++) {
          int growb = r0 + wm * 64 + ms * 16 + lg * 4;
          #pragma unroll
          for (int ns = 0; ns < 2; ns++) {
            int gcol = ctile + wn * 32 + ns * 16 + ll;
            #pragma unroll
            for (int r = 0; r < 4; r++) {
              float sv = (growb + r == gcol) ? -3.0e38f : acc[ms][ns][r];
              lacc[ms][r] += __builtin_amdgcn_exp2f((sv - 1.0f) * kScale);
            }
          }
        }
      } else {
        #pragma unroll
        for (int ms = 0; ms < 4; ms++)
          #pragma unroll
          for (int ns = 0; ns < 2; ns++)
            #pragma unroll
            for (int r = 0; r < 4; r++)
              lacc[ms][r] += __builtin_amdgcn_exp2f((acc[ms][ns][r] - 1.0f) * kScale);
      }
    }

    // reduce partial l across the 16 lanes of each group; (strip, wn) slots.
    #pragma unroll
    for (int ms = 0; ms < 4; ms++)
      #pragma unroll
      for (int r = 0; r < 4; r++) {
        float v = lacc[ms][r];
        v += __shfl_xor(v, 1); v += __shfl_xor(v, 2);
        v += __shfl_xor(v, 4); v += __shfl_xor(v, 8);
        lacc[ms][r] = v;
      }
    if (ll == 0) {
      int slot = (g & 7) * 2 + wn;   // 16 slots
      #pragma unroll
      for (int ms = 0; ms < 4; ms++)
        #pragma unroll
        for (int r = 0; r < 4; r++) {
          int grow = r0 + wm * 64 + ms * 16 + lg * 4 + r;
          lpart[(size_t)slot * NN + grow] = lacc[ms][r];
        }
    }
  } else {
    // ---- scan half (r4 exact): 8-deep load batches over label ----
    int sg = sub;                            // 0..511
    const u32x4* L = (const u32x4*)label;
    int t = sg * 256 + tid;                  // 131072 scan threads
    for (int k = 0; k < 16; k++) {
      u32x4 v[8];
      #pragma unroll
      for (int j = 0; j < 8; j++)
        v[j] = L[t + (k * 8 + j) * 131072];
      unsigned any = 0;
      #pragma unroll
      for (int j = 0; j < 8; j++) any |= v[j][0] | v[j][1] | v[j][2] | v[j][3];
      if (any) {
        #pragma unroll
        for (int j = 0; j < 8; j++) {
          int idx = t + (k * 8 + j) * 131072;
          if (v[j][0] | v[j][1] | v[j][2] | v[j][3]) {
            int gi = idx * 4;
            int row = gi >> 13, col = gi & (NN - 1);
            if (v[j][0] == 1u) pos_idx[row] = col;
            if (v[j][1] == 1u) pos_idx[row] = col + 1;
            if (v[j][2] == 1u) pos_idx[row] = col + 2;
            if (v[j][3] == 1u) pos_idx[row] = col + 3;
          }
        }
      }
    }
  }
}

// ---------------- k3: per-row lse + positive, atomic mean ----------------
__global__ __launch_bounds__(256) void k_finalize(const unsigned short* __restrict__ nfb,
                                                  const float* __restrict__ lpart,
                                                  const int* __restrict__ pos_idx,
                                                  float* __restrict__ out) {
  int i = blockIdx.x * 256 + threadIdx.x;
  float l = 0.f;
  #pragma unroll
  for (int s = 0; s < 16; s++) l += lpart[(size_t)s * NN + i];
  float lse = kM + __builtin_amdgcn_logf(l) * kLn2;
  int p = pos_idx[i] & (NN - 1);
  const u32x4* ri = (const u32x4*)(nfb + (size_t)i * DD);
  const u32x4* rp = (const u32x4*)(nfb + (size_t)p * DD);
  float dot = 0.f;
  #pragma unroll
  for (int c = 0; c < 16; c++) {
    u32x4 a = ri[c], bb = rp[c];
    #pragma unroll
    for (int e = 0; e < 4; e++) {
      float al = __uint_as_float(a[e] << 16), ah = __uint_as_float(a[e] & 0xFFFF0000u);
      float bl = __uint_as_float(bb[e] << 16), bh = __uint_as_float(bb[e] & 0xFFFF0000u);
      dot += al * bl + ah * bh;
    }
  }
  float val = lse - dot * kM;   // pos = dot / T
  #pragma unroll
  for (int m = 1; m < 64; m <<= 1) val += __shfl_xor(val, m);
  __shared__ float wsum[4];
  if ((threadIdx.x & 63) == 0) wsum[threadIdx.x >> 6] = val;
  __syncthreads();
  if (threadIdx.x == 0)
    atomicAdd(out, (wsum[0] + wsum[1] + wsum[2] + wsum[3]) * (1.0f / (float)NN));
}

extern "C" void kernel_launch(void* const* d_in, const int* in_sizes, int n_in,
                              void* d_out, int out_size, void* d_ws, size_t ws_size,
                              hipStream_t stream) {
  (void)in_sizes; (void)n_in; (void)out_size; (void)ws_size;
  const float* feats = (const float*)d_in[0];
  const int* label = (const int*)d_in[1];
  float* out = (float*)d_out;

  char* ws = (char*)d_ws;
  unsigned short* nfb = (unsigned short*)ws;                    // 2 MB
  float* lpart = (float*)(ws + 2 * 1024 * 1024);                // 512 KB (16 slots)
  int* pos_idx = (int*)(ws + 2 * 1024 * 1024 + 524288);         // 32 KB

  hipMemsetAsync(out, 0, sizeof(float), stream);
  k_normalize<<<NN / 4, 256, 0, stream>>>(feats, nfb);
  k_fused<<<1024, 256, 0, stream>>>(nfb, label, lpart, pos_idx);
  k_finalize<<<NN / 256, 256, 0, stream>>>(nfb, lpart, pos_idx, out);
}